// Round 1
// baseline (91.214 us; speedup 1.0000x reference)
//
#include <hip/hip_runtime.h>
#include <stdint.h>

// Problem: B=4, H=16, L=8192, D=64, fp32.
// out = v with row0 <- per-column max, row argmax <- original row0 value.
// Output tuple (new_v, new_v) concatenated.

#define LL 8192
#define DD 64
#define NS 64                 // B*H slices
#define BLOCKS_PER_SLICE 32
#define ROWS_PER_BLOCK 256    // 8192 / 32

__device__ __forceinline__ uint32_t float_to_key(float f) {
    uint32_t u = __float_as_uint(f);
    return (u & 0x80000000u) ? ~u : (u | 0x80000000u);
}
__device__ __forceinline__ float key_to_float(uint32_t k) {
    uint32_t u = (k & 0x80000000u) ? (k & 0x7FFFFFFFu) : ~k;
    return __uint_as_float(u);
}
__device__ __forceinline__ unsigned long long shfl_xor_u64(unsigned long long x, int mask) {
    int lo = (int)(uint32_t)(x & 0xFFFFFFFFull);
    int hi = (int)(uint32_t)(x >> 32);
    lo = __shfl_xor(lo, mask, 64);
    hi = __shfl_xor(hi, mask, 64);
    return ((unsigned long long)(uint32_t)hi << 32) | (uint32_t)lo;
}

__global__ void init_ws_kernel(unsigned long long* ws) {
    int i = blockIdx.x * blockDim.x + threadIdx.x;
    if (i < NS * DD) ws[i] = 0ULL;
}

__global__ __launch_bounds__(256) void copy_reduce_kernel(
        const float* __restrict__ v,
        float* __restrict__ out0,
        float* __restrict__ out1,
        unsigned long long* __restrict__ ws) {
    const int s = blockIdx.x / BLOCKS_PER_SLICE;
    const int c = blockIdx.x % BLOCKS_PER_SLICE;
    const int t = threadIdx.x;
    const int q  = t & 15;   // which float4 within a row (4 d-columns)
    const int r0 = t >> 4;   // row offset within 16-row stripe
    const size_t slice_off = (size_t)s * LL * DD;
    const int base_row = c * ROWS_PER_BLOCK;

    float maxv[4];
    int   maxi[4];
#pragma unroll
    for (int j = 0; j < 4; ++j) { maxv[j] = -INFINITY; maxi[j] = 0x7FFFFFFF; }

    // 16 iterations: each iteration the block covers 16 consecutive rows
    // (256 threads x 16B = 4KB contiguous per load/store -> fully coalesced).
#pragma unroll 4
    for (int i = 0; i < ROWS_PER_BLOCK / 16; ++i) {
        const int l = base_row + i * 16 + r0;
        const size_t off = slice_off + (size_t)l * DD + q * 4;
        float4 val = *reinterpret_cast<const float4*>(v + off);
        *reinterpret_cast<float4*>(out0 + off) = val;
        *reinterpret_cast<float4*>(out1 + off) = val;
        float vv[4] = {val.x, val.y, val.z, val.w};
#pragma unroll
        for (int j = 0; j < 4; ++j) {
            // strict > keeps the FIRST occurrence (l increases monotonically per thread)
            if (vv[j] > maxv[j]) { maxv[j] = vv[j]; maxi[j] = l; }
        }
    }

    // pack: larger value wins; on value tie, smaller index wins (via ~idx)
    unsigned long long p[4];
#pragma unroll
    for (int j = 0; j < 4; ++j)
        p[j] = ((unsigned long long)float_to_key(maxv[j]) << 32) |
               (unsigned long long)(uint32_t)(~(uint32_t)maxi[j]);

    // reduce across lanes that share the same q (lanes differ in bits 4,5 within a wave)
#pragma unroll
    for (int j = 0; j < 4; ++j) {
        unsigned long long o = shfl_xor_u64(p[j], 16);
        if (o > p[j]) p[j] = o;
        o = shfl_xor_u64(p[j], 32);
        if (o > p[j]) p[j] = o;
    }

    __shared__ unsigned long long red[4 * 64];
    const int w    = t >> 6;  // wave id 0..3
    const int lane = t & 63;
    if (lane < 16) {
#pragma unroll
        for (int j = 0; j < 4; ++j) red[w * 64 + lane * 4 + j] = p[j];
    }
    __syncthreads();
    if (t < 64) {
        unsigned long long m = red[t];
        if (red[64 + t]  > m) m = red[64 + t];
        if (red[128 + t] > m) m = red[128 + t];
        if (red[192 + t] > m) m = red[192 + t];
        atomicMax(&ws[s * DD + t], m);
    }
}

__global__ void patch_kernel(const float* __restrict__ v,
                             float* __restrict__ out0,
                             float* __restrict__ out1,
                             const unsigned long long* __restrict__ ws) {
    int i = blockIdx.x * blockDim.x + threadIdx.x;
    if (i >= NS * DD) return;
    const int s = i / DD;
    const int d = i % DD;
    const unsigned long long p = ws[i];
    const uint32_t key = (uint32_t)(p >> 32);
    const int idx = (int)(~(uint32_t)(p & 0xFFFFFFFFull));
    const float maxval = key_to_float(key);
    const size_t base = (size_t)s * LL * DD + d;
    const float v0 = v[base];
    // row 0 <- max; row idx <- original row-0 value. When idx==0 both equal v0.
    out0[base] = maxval;
    out1[base] = maxval;
    const size_t at = base + (size_t)idx * DD;
    out0[at] = v0;
    out1[at] = v0;
}

extern "C" void kernel_launch(void* const* d_in, const int* in_sizes, int n_in,
                              void* d_out, int out_size, void* d_ws, size_t ws_size,
                              hipStream_t stream) {
    // inputs: q, k, v (only v used)
    const float* v = (const float*)d_in[2];
    float* out0 = (float*)d_out;
    float* out1 = out0 + (size_t)NS * LL * DD;
    unsigned long long* ws = (unsigned long long*)d_ws;

    init_ws_kernel<<<(NS * DD + 255) / 256, 256, 0, stream>>>(ws);
    copy_reduce_kernel<<<NS * BLOCKS_PER_SLICE, 256, 0, stream>>>(v, out0, out1, ws);
    patch_kernel<<<(NS * DD + 255) / 256, 256, 0, stream>>>(v, out0, out1, ws);
}

// Round 2
// 83.015 us; speedup vs baseline: 1.0988x; 1.0988x over previous
//
#include <hip/hip_runtime.h>
#include <stdint.h>

// Problem: B=4, H=16, L=8192, D=64, fp32.
// out = v with row0 <- per-column max, row argmax <- original row0 value.
// Output tuple (new_v, new_v) concatenated. q,k unused.

#define LL 8192
#define DD 64
#define NS 64                 // B*H slices
#define BLOCKS_PER_SLICE 32
#define ROWS_PER_BLOCK 256    // 8192 / 32

typedef float f32x4 __attribute__((ext_vector_type(4)));
typedef unsigned long long u64;

__device__ __forceinline__ uint32_t float_to_key(float f) {
    uint32_t u = __float_as_uint(f);
    return (u & 0x80000000u) ? ~u : (u | 0x80000000u);
}
__device__ __forceinline__ float key_to_float(uint32_t k) {
    uint32_t u = (k & 0x80000000u) ? (k & 0x7FFFFFFFu) : ~k;
    return __uint_as_float(u);
}
__device__ __forceinline__ u64 shfl_xor_u64(u64 x, int mask) {
    int lo = (int)(uint32_t)(x & 0xFFFFFFFFull);
    int hi = (int)(uint32_t)(x >> 32);
    lo = __shfl_xor(lo, mask, 64);
    hi = __shfl_xor(hi, mask, 64);
    return ((u64)(uint32_t)hi << 32) | (uint32_t)lo;
}

// ---------- shared body: copy + per-block (max,argmax) partials ----------
// Returns packed partials for this block's 64 columns in red[0..63] (LDS),
// valid for threads t<64 after the final __syncthreads-free read.
template <bool USE_SLOTS>
__global__ __launch_bounds__(256) void copy_reduce_kernel(
        const float* __restrict__ v,
        float* __restrict__ out0,
        float* __restrict__ out1,
        u64* __restrict__ ws) {
    const int s = blockIdx.x / BLOCKS_PER_SLICE;
    const int c = blockIdx.x % BLOCKS_PER_SLICE;
    const int t = threadIdx.x;
    const int q  = t & 15;   // which float4 within a row (4 d-columns)
    const int r0 = t >> 4;   // row offset within 16-row stripe
    const size_t slice_off = (size_t)s * LL * DD;
    const int base_row = c * ROWS_PER_BLOCK;

    float maxv[4];
    int   maxi[4];
#pragma unroll
    for (int j = 0; j < 4; ++j) { maxv[j] = -INFINITY; maxi[j] = 0x7FFFFFFF; }

    // 16 iterations: each covers 16 consecutive rows
    // (256 threads x 16B = 4KB contiguous -> fully coalesced, full lines).
#pragma unroll 4
    for (int i = 0; i < ROWS_PER_BLOCK / 16; ++i) {
        const int l = base_row + i * 16 + r0;
        const size_t off = slice_off + (size_t)l * DD + q * 4;
        f32x4 val = __builtin_nontemporal_load(reinterpret_cast<const f32x4*>(v + off));
        __builtin_nontemporal_store(val, reinterpret_cast<f32x4*>(out0 + off));
        __builtin_nontemporal_store(val, reinterpret_cast<f32x4*>(out1 + off));
#pragma unroll
        for (int j = 0; j < 4; ++j) {
            // strict > keeps FIRST occurrence (l increases monotonically per thread)
            if (val[j] > maxv[j]) { maxv[j] = val[j]; maxi[j] = l; }
        }
    }

    // pack: larger value wins; on value tie, smaller index wins (via ~idx)
    u64 p[4];
#pragma unroll
    for (int j = 0; j < 4; ++j)
        p[j] = ((u64)float_to_key(maxv[j]) << 32) | (u64)(uint32_t)(~(uint32_t)maxi[j]);

    // reduce across lanes sharing q (differ in lane bits 4,5)
#pragma unroll
    for (int j = 0; j < 4; ++j) {
        u64 o = shfl_xor_u64(p[j], 16);
        if (o > p[j]) p[j] = o;
        o = shfl_xor_u64(p[j], 32);
        if (o > p[j]) p[j] = o;
    }

    __shared__ u64 red[4 * 64];
    const int w    = t >> 6;  // wave id 0..3
    const int lane = t & 63;
    if (lane < 16) {
#pragma unroll
        for (int j = 0; j < 4; ++j) red[w * 64 + lane * 4 + j] = p[j];  // col d = lane*4+j
    }
    __syncthreads();
    if (t < 64) {
        u64 m = red[t];
        if (red[64 + t]  > m) m = red[64 + t];
        if (red[128 + t] > m) m = red[128 + t];
        if (red[192 + t] > m) m = red[192 + t];
        if (USE_SLOTS) {
            ws[((size_t)s * BLOCKS_PER_SLICE + c) * DD + t] = m;  // distinct slot: no atomics, no init
        } else {
            atomicMax(&ws[s * DD + t], m);
        }
    }
}

__global__ void init_ws_kernel(u64* ws) {
    int i = blockIdx.x * blockDim.x + threadIdx.x;
    if (i < NS * DD) ws[i] = 0ULL;
}

__device__ __forceinline__ void apply_patch(const float* v, float* out0, float* out1,
                                            int s, int d, u64 p) {
    const float maxval = key_to_float((uint32_t)(p >> 32));
    const int idx = (int)(~(uint32_t)(p & 0xFFFFFFFFull));
    const size_t base = (size_t)s * LL * DD + d;
    const float v0 = v[base];
    out0[base] = maxval;
    out1[base] = maxval;
    const size_t at = base + (size_t)idx * DD;
    out0[at] = v0;   // when idx==0 both writes equal v0==maxval
    out1[at] = v0;
}

// slot-path patch: reduce 32 partials per column, then patch
__global__ void patch_slots_kernel(const float* __restrict__ v,
                                   float* __restrict__ out0,
                                   float* __restrict__ out1,
                                   const u64* __restrict__ ws) {
    int i = blockIdx.x * blockDim.x + threadIdx.x;
    if (i >= NS * DD) return;
    const int s = i >> 6;
    const int d = i & 63;
    const u64* base = ws + (size_t)s * BLOCKS_PER_SLICE * DD + d;
    u64 m = 0;
#pragma unroll
    for (int c = 0; c < BLOCKS_PER_SLICE; ++c) {
        u64 x = base[(size_t)c * DD];
        if (x > m) m = x;
    }
    apply_patch(v, out0, out1, s, d, m);
}

// atomic-path patch
__global__ void patch_atomic_kernel(const float* __restrict__ v,
                                    float* __restrict__ out0,
                                    float* __restrict__ out1,
                                    const u64* __restrict__ ws) {
    int i = blockIdx.x * blockDim.x + threadIdx.x;
    if (i >= NS * DD) return;
    apply_patch(v, out0, out1, i >> 6, i & 63, ws[i]);
}

extern "C" void kernel_launch(void* const* d_in, const int* in_sizes, int n_in,
                              void* d_out, int out_size, void* d_ws, size_t ws_size,
                              hipStream_t stream) {
    const float* v = (const float*)d_in[2];   // inputs: q, k, v
    float* out0 = (float*)d_out;
    float* out1 = out0 + (size_t)NS * LL * DD;
    u64* ws = (u64*)d_ws;

    const size_t slots_bytes = (size_t)NS * BLOCKS_PER_SLICE * DD * sizeof(u64); // 1 MiB
    if (ws_size >= slots_bytes) {
        copy_reduce_kernel<true><<<NS * BLOCKS_PER_SLICE, 256, 0, stream>>>(v, out0, out1, ws);
        patch_slots_kernel<<<(NS * DD + 255) / 256, 256, 0, stream>>>(v, out0, out1, ws);
    } else {
        init_ws_kernel<<<(NS * DD + 255) / 256, 256, 0, stream>>>(ws);
        copy_reduce_kernel<false><<<NS * BLOCKS_PER_SLICE, 256, 0, stream>>>(v, out0, out1, ws);
        patch_atomic_kernel<<<(NS * DD + 255) / 256, 256, 0, stream>>>(v, out0, out1, ws);
    }
}

// Round 3
// 67.853 us; speedup vs baseline: 1.3443x; 1.2235x over previous
//
#include <hip/hip_runtime.h>
#include <stdint.h>

// Problem: B=4, H=16, L=8192, D=64, fp32.
// out = v with row0 <- per-column max, row argmax <- original row0 value.
// Output tuple (new_v, new_v) concatenated. q,k unused.
//
// Policy: v (134 MB) fits in the 256 MB Infinity Cache -> use TEMPORAL loads
// so v stays L3-resident across graph replays; outputs are write-once ->
// NON-TEMPORAL stores so the 268 MB write stream doesn't evict v from L3.

#define LL 8192
#define DD 64
#define NS 64                 // B*H slices
#define BLOCKS_PER_SLICE 32
#define ROWS_PER_BLOCK 256    // 8192 / 32

typedef float f32x4 __attribute__((ext_vector_type(4)));
typedef unsigned long long u64;

__device__ __forceinline__ uint32_t float_to_key(float f) {
    uint32_t u = __float_as_uint(f);
    return (u & 0x80000000u) ? ~u : (u | 0x80000000u);
}
__device__ __forceinline__ float key_to_float(uint32_t k) {
    uint32_t u = (k & 0x80000000u) ? (k & 0x7FFFFFFFu) : ~k;
    return __uint_as_float(u);
}
__device__ __forceinline__ u64 shfl_xor_u64(u64 x, int mask) {
    int lo = (int)(uint32_t)(x & 0xFFFFFFFFull);
    int hi = (int)(uint32_t)(x >> 32);
    lo = __shfl_xor(lo, mask, 64);
    hi = __shfl_xor(hi, mask, 64);
    return ((u64)(uint32_t)hi << 32) | (uint32_t)lo;
}

template <bool USE_SLOTS>
__global__ __launch_bounds__(256) void copy_reduce_kernel(
        const float* __restrict__ v,
        float* __restrict__ out0,
        float* __restrict__ out1,
        u64* __restrict__ ws) {
    const int s = blockIdx.x / BLOCKS_PER_SLICE;
    const int c = blockIdx.x % BLOCKS_PER_SLICE;
    const int t = threadIdx.x;
    const int q  = t & 15;   // which float4 within a row (4 d-columns)
    const int r0 = t >> 4;   // row offset within 16-row stripe
    const size_t slice_off = (size_t)s * LL * DD;
    const int base_row = c * ROWS_PER_BLOCK;

    float maxv[4];
    int   maxi[4];
#pragma unroll
    for (int j = 0; j < 4; ++j) { maxv[j] = -INFINITY; maxi[j] = 0x7FFFFFFF; }

    // 16 iterations: each covers 16 consecutive rows
    // (256 threads x 16B = 4KB contiguous -> fully coalesced, full lines).
#pragma unroll 8
    for (int i = 0; i < ROWS_PER_BLOCK / 16; ++i) {
        const int l = base_row + i * 16 + r0;
        const size_t off = slice_off + (size_t)l * DD + q * 4;
        f32x4 val = *reinterpret_cast<const f32x4*>(v + off);          // temporal: keep v in L3
        __builtin_nontemporal_store(val, reinterpret_cast<f32x4*>(out0 + off));
        __builtin_nontemporal_store(val, reinterpret_cast<f32x4*>(out1 + off));
#pragma unroll
        for (int j = 0; j < 4; ++j) {
            // strict > keeps FIRST occurrence (l increases monotonically per thread)
            if (val[j] > maxv[j]) { maxv[j] = val[j]; maxi[j] = l; }
        }
    }

    // pack: larger value wins; on value tie, smaller index wins (via ~idx)
    u64 p[4];
#pragma unroll
    for (int j = 0; j < 4; ++j)
        p[j] = ((u64)float_to_key(maxv[j]) << 32) | (u64)(uint32_t)(~(uint32_t)maxi[j]);

    // reduce across lanes sharing q (differ in lane bits 4,5)
#pragma unroll
    for (int j = 0; j < 4; ++j) {
        u64 o = shfl_xor_u64(p[j], 16);
        if (o > p[j]) p[j] = o;
        o = shfl_xor_u64(p[j], 32);
        if (o > p[j]) p[j] = o;
    }

    __shared__ u64 red[4 * 64];
    const int w    = t >> 6;  // wave id 0..3
    const int lane = t & 63;
    if (lane < 16) {
#pragma unroll
        for (int j = 0; j < 4; ++j) red[w * 64 + lane * 4 + j] = p[j];  // col d = lane*4+j
    }
    __syncthreads();
    if (t < 64) {
        u64 m = red[t];
        if (red[64 + t]  > m) m = red[64 + t];
        if (red[128 + t] > m) m = red[128 + t];
        if (red[192 + t] > m) m = red[192 + t];
        if (USE_SLOTS) {
            ws[((size_t)s * BLOCKS_PER_SLICE + c) * DD + t] = m;  // distinct slot: no atomics, no init
        } else {
            atomicMax(&ws[s * DD + t], m);
        }
    }
}

__global__ void init_ws_kernel(u64* ws) {
    int i = blockIdx.x * blockDim.x + threadIdx.x;
    if (i < NS * DD) ws[i] = 0ULL;
}

__device__ __forceinline__ void apply_patch(const float* v, float* out0, float* out1,
                                            int s, int d, u64 p) {
    const float maxval = key_to_float((uint32_t)(p >> 32));
    const int idx = (int)(~(uint32_t)(p & 0xFFFFFFFFull));
    const size_t base = (size_t)s * LL * DD + d;
    const float v0 = v[base];
    out0[base] = maxval;
    out1[base] = maxval;
    const size_t at = base + (size_t)idx * DD;
    out0[at] = v0;   // when idx==0 both writes equal v0==maxval
    out1[at] = v0;
}

// slot-path patch: reduce 32 partials per column, then patch
__global__ void patch_slots_kernel(const float* __restrict__ v,
                                   float* __restrict__ out0,
                                   float* __restrict__ out1,
                                   const u64* __restrict__ ws) {
    int i = blockIdx.x * blockDim.x + threadIdx.x;
    if (i >= NS * DD) return;
    const int s = i >> 6;
    const int d = i & 63;
    const u64* base = ws + (size_t)s * BLOCKS_PER_SLICE * DD + d;
    u64 m = 0;
#pragma unroll
    for (int c = 0; c < BLOCKS_PER_SLICE; ++c) {
        u64 x = base[(size_t)c * DD];
        if (x > m) m = x;
    }
    apply_patch(v, out0, out1, s, d, m);
}

// atomic-path patch
__global__ void patch_atomic_kernel(const float* __restrict__ v,
                                    float* __restrict__ out0,
                                    float* __restrict__ out1,
                                    const u64* __restrict__ ws) {
    int i = blockIdx.x * blockDim.x + threadIdx.x;
    if (i >= NS * DD) return;
    apply_patch(v, out0, out1, i >> 6, i & 63, ws[i]);
}

extern "C" void kernel_launch(void* const* d_in, const int* in_sizes, int n_in,
                              void* d_out, int out_size, void* d_ws, size_t ws_size,
                              hipStream_t stream) {
    const float* v = (const float*)d_in[2];   // inputs: q, k, v
    float* out0 = (float*)d_out;
    float* out1 = out0 + (size_t)NS * LL * DD;
    u64* ws = (u64*)d_ws;

    const size_t slots_bytes = (size_t)NS * BLOCKS_PER_SLICE * DD * sizeof(u64); // 1 MiB
    if (ws_size >= slots_bytes) {
        copy_reduce_kernel<true><<<NS * BLOCKS_PER_SLICE, 256, 0, stream>>>(v, out0, out1, ws);
        patch_slots_kernel<<<(NS * DD + 255) / 256, 256, 0, stream>>>(v, out0, out1, ws);
    } else {
        init_ws_kernel<<<(NS * DD + 255) / 256, 256, 0, stream>>>(ws);
        copy_reduce_kernel<false><<<NS * BLOCKS_PER_SLICE, 256, 0, stream>>>(v, out0, out1, ws);
        patch_atomic_kernel<<<(NS * DD + 255) / 256, 256, 0, stream>>>(v, out0, out1, ws);
    }
}